// Round 1
// baseline (2005.294 us; speedup 1.0000x reference)
//
#include <hip/hip_runtime.h>
#include <hip/hip_bf16.h>
#include <math.h>

#define B_ 4
#define S_ 1024
#define H_ 512
#define NH_ 8
#define HD_ 64
#define FF_ 1024
#define E_ 4
#define L_ 4
#define NT_ 17
#define BS_ 4096
#define EPS_ 1e-5f

// ---------------------------------------------------------------------------
// k_init: x = emb[patches] (or emb[16] where mask), biasum[l][r] = sum_d relemb
// ---------------------------------------------------------------------------
__global__ __launch_bounds__(256) void k_init(const int* __restrict__ patches,
                                              const int* __restrict__ mask,
                                              const float* __restrict__ emb,
                                              const float* __restrict__ relemb,
                                              float* __restrict__ x,
                                              float* __restrict__ biasum) {
  int gid = blockIdx.x * 256 + threadIdx.x;
  if (gid < BS_) {
    int p = patches[gid];
    int mk = mask[gid];
    int row = mk ? (NT_ - 1) : p;
    float4 v = ((const float4*)emb)[row];
    ((float4*)x)[gid] = v;
  } else {
    int r = gid - BS_;
    if (r < L_ * 63) {
      const float* src = relemb + r * 64;
      float s = 0.f;
#pragma unroll
      for (int d = 0; d < 64; d++) s += src[d];
      biasum[r] = s;
    }
  }
}

// ---------------------------------------------------------------------------
// k_inln: xp = x @ Wi + bi ; xn = layernorm(xp)*g1 + b1n.  One block per token.
// ---------------------------------------------------------------------------
__global__ __launch_bounds__(256) void k_inln(const float* __restrict__ x,
                                              const float* __restrict__ Wi,
                                              const float* __restrict__ bi,
                                              const float* __restrict__ g1,
                                              const float* __restrict__ b1n,
                                              float* __restrict__ xn) {
  __shared__ float red_s[4], red_q[4];
  int tok = blockIdx.x;
  int t = threadIdx.x;
  float4 xr = ((const float4*)x)[tok];
  int j0 = t, j1 = t + 256;
  float xp0 = bi[j0] + xr.x * Wi[j0] + xr.y * Wi[H_ + j0] + xr.z * Wi[2 * H_ + j0] + xr.w * Wi[3 * H_ + j0];
  float xp1 = bi[j1] + xr.x * Wi[j1] + xr.y * Wi[H_ + j1] + xr.z * Wi[2 * H_ + j1] + xr.w * Wi[3 * H_ + j1];
  float s = xp0 + xp1;
  float q = xp0 * xp0 + xp1 * xp1;
#pragma unroll
  for (int o = 32; o > 0; o >>= 1) {
    s += __shfl_xor(s, o);
    q += __shfl_xor(q, o);
  }
  int wid = t >> 6;
  if ((t & 63) == 0) { red_s[wid] = s; red_q[wid] = q; }
  __syncthreads();
  s = red_s[0] + red_s[1] + red_s[2] + red_s[3];
  q = red_q[0] + red_q[1] + red_q[2] + red_q[3];
  float mean = s * (1.f / (float)H_);
  float var = q * (1.f / (float)H_) - mean * mean;
  float rs = rsqrtf(var + EPS_);
  xn[tok * H_ + j0] = (xp0 - mean) * rs * g1[j0] + b1n[j0];
  xn[tok * H_ + j1] = (xp1 - mean) * rs * g1[j1] + b1n[j1];
}

// ---------------------------------------------------------------------------
// k_qkv: C(4096x1536) = A(4096x512) @ B(512x1536) + bias.  fp32 tiled GEMM.
// 128x128 block tile, BK=16, 256 threads, 8x8 microtile.
// ---------------------------------------------------------------------------
#define QBM 128
#define QBN 128
#define QBK 16
__global__ __launch_bounds__(256) void k_qkv(const float* __restrict__ A,
                                             const float* __restrict__ Bw,
                                             const float* __restrict__ bias,
                                             float* __restrict__ C) {
  __shared__ float As[QBK][QBM + 4];
  __shared__ float Bs[QBK][QBN + 4];
  const int K = H_, N = 3 * H_;
  int t = threadIdx.x;
  int m0 = blockIdx.y * QBM, n0 = blockIdx.x * QBN;
  int tr = t >> 4, tc = t & 15;
  float acc[8][8];
#pragma unroll
  for (int i = 0; i < 8; i++)
#pragma unroll
    for (int j = 0; j < 8; j++) acc[i][j] = 0.f;
  int ar = t >> 1, akb = (t & 1) * 8;
  int bkr = t >> 4, bnb = (t & 15) * 8;
  for (int k0 = 0; k0 < K; k0 += QBK) {
    float4 a0 = *(const float4*)&A[(m0 + ar) * K + k0 + akb];
    float4 a1 = *(const float4*)&A[(m0 + ar) * K + k0 + akb + 4];
    float4 b0 = *(const float4*)&Bw[(size_t)(k0 + bkr) * N + n0 + bnb];
    float4 b1 = *(const float4*)&Bw[(size_t)(k0 + bkr) * N + n0 + bnb + 4];
    As[akb + 0][ar] = a0.x; As[akb + 1][ar] = a0.y; As[akb + 2][ar] = a0.z; As[akb + 3][ar] = a0.w;
    As[akb + 4][ar] = a1.x; As[akb + 5][ar] = a1.y; As[akb + 6][ar] = a1.z; As[akb + 7][ar] = a1.w;
    *(float4*)&Bs[bkr][bnb] = b0;
    *(float4*)&Bs[bkr][bnb + 4] = b1;
    __syncthreads();
#pragma unroll
    for (int kk = 0; kk < QBK; kk++) {
      float4 av0 = *(float4*)&As[kk][tr * 8];
      float4 av1 = *(float4*)&As[kk][tr * 8 + 4];
      float4 bv0 = *(float4*)&Bs[kk][tc * 8];
      float4 bv1 = *(float4*)&Bs[kk][tc * 8 + 4];
      float a_[8] = {av0.x, av0.y, av0.z, av0.w, av1.x, av1.y, av1.z, av1.w};
      float b_[8] = {bv0.x, bv0.y, bv0.z, bv0.w, bv1.x, bv1.y, bv1.z, bv1.w};
#pragma unroll
      for (int i = 0; i < 8; i++)
#pragma unroll
        for (int j = 0; j < 8; j++) acc[i][j] += a_[i] * b_[j];
    }
    __syncthreads();
  }
#pragma unroll
  for (int i = 0; i < 8; i++) {
    int row = m0 + tr * 8 + i;
    int col = n0 + tc * 8;
    float4 o0 = make_float4(acc[i][0] + bias[col + 0], acc[i][1] + bias[col + 1],
                            acc[i][2] + bias[col + 2], acc[i][3] + bias[col + 3]);
    float4 o1 = make_float4(acc[i][4] + bias[col + 4], acc[i][5] + bias[col + 5],
                            acc[i][6] + bias[col + 6], acc[i][7] + bias[col + 7]);
    *(float4*)&C[(size_t)row * N + col] = o0;
    *(float4*)&C[(size_t)row * N + col + 4] = o1;
  }
}

// ---------------------------------------------------------------------------
// k_attn: flash attention, fp32.  Block = (b, h, 64 q rows), K-tiles of 32.
// thread (tr,tc): rows {tr+16i}, score cols {tc+16j}, out dims {tc+16j}.
// ---------------------------------------------------------------------------
__global__ __launch_bounds__(256) void k_attn(const float* __restrict__ qkv,
                                              const int* __restrict__ mask,
                                              const float* __restrict__ biasum,
                                              float* __restrict__ ao) {
  __shared__ float Qt[64][68];
  __shared__ float Kt[32][68];
  __shared__ float Vt[64][36];  // [d][c] (transposed)
  __shared__ float Pt[64][36];  // [r][c]
  __shared__ float m_l[64], l_l[64];
  int t = threadIdx.x;
  int tr = t >> 4, tc = t & 15;
  int q0 = blockIdx.x * 64;
  int h = blockIdx.y, b = blockIdx.z;
  const float scale = 0.125f;

  {  // stage Q (pre-scaled)
    int r = t >> 2, db = (t & 3) * 16;
    const float* src = qkv + ((size_t)((b * S_ + q0 + r) * 3 + 0)) * H_ + h * HD_ + db;
#pragma unroll
    for (int c4 = 0; c4 < 4; c4++) {
      float4 v = *(const float4*)(src + c4 * 4);
      v.x *= scale; v.y *= scale; v.z *= scale; v.w *= scale;
      *(float4*)&Qt[r][db + c4 * 4] = v;
    }
  }
  if (t < 64) { m_l[t] = -INFINITY; l_l[t] = 0.f; }
  float o_[4][4];
#pragma unroll
  for (int i = 0; i < 4; i++)
#pragma unroll
    for (int j = 0; j < 4; j++) o_[i][j] = 0.f;

  for (int k0 = 0; k0 < S_; k0 += 32) {
    __syncthreads();  // prev PV done (Vt/Kt free); also first-iter Qt/m_l visible
    {  // stage K tile
      int r = t >> 3, db = (t & 7) * 8;
      const float* src = qkv + ((size_t)((b * S_ + k0 + r) * 3 + 1)) * H_ + h * HD_ + db;
      float4 v0 = *(const float4*)src;
      float4 v1 = *(const float4*)(src + 4);
      *(float4*)&Kt[r][db] = v0;
      *(float4*)&Kt[r][db + 4] = v1;
    }
    {  // stage V tile transposed
      int c = t >> 3, db = (t & 7) * 8;
      const float* src = qkv + ((size_t)((b * S_ + k0 + c) * 3 + 2)) * H_ + h * HD_ + db;
      float4 v0 = *(const float4*)src;
      float4 v1 = *(const float4*)(src + 4);
      Vt[db + 0][c] = v0.x; Vt[db + 1][c] = v0.y; Vt[db + 2][c] = v0.z; Vt[db + 3][c] = v0.w;
      Vt[db + 4][c] = v1.x; Vt[db + 5][c] = v1.y; Vt[db + 6][c] = v1.z; Vt[db + 7][c] = v1.w;
    }
    __syncthreads();

    // scores S = Q.K^T (Q prescaled)
    float s_[4][2];
#pragma unroll
    for (int i = 0; i < 4; i++) { s_[i][0] = 0.f; s_[i][1] = 0.f; }
    for (int d = 0; d < HD_; d += 4) {
      float4 qv[4], kv[2];
#pragma unroll
      for (int i = 0; i < 4; i++) qv[i] = *(float4*)&Qt[tr + 16 * i][d];
#pragma unroll
      for (int j = 0; j < 2; j++) kv[j] = *(float4*)&Kt[tc + 16 * j][d];
#pragma unroll
      for (int i = 0; i < 4; i++)
#pragma unroll
        for (int j = 0; j < 2; j++)
          s_[i][j] += qv[i].x * kv[j].x + qv[i].y * kv[j].y + qv[i].z * kv[j].z + qv[i].w * kv[j].w;
    }
    // bias + mask
    int kg[2]; int mk[2];
#pragma unroll
    for (int j = 0; j < 2; j++) { kg[j] = k0 + tc + 16 * j; mk[j] = mask[b * S_ + kg[j]]; }
#pragma unroll
    for (int i = 0; i < 4; i++) {
      int qg = q0 + tr + 16 * i;
#pragma unroll
      for (int j = 0; j < 2; j++) {
        if (mk[j] && qg != kg[j]) {
          s_[i][j] = -INFINITY;
        } else {
          int rel = qg - kg[j] + 31;
          rel = rel < 0 ? 0 : (rel > 62 ? 62 : rel);
          s_[i][j] += biasum[rel];
        }
      }
    }
    // online softmax (row group = 16 contiguous lanes of one wave)
    float mt[4], lt[4], al[4];
#pragma unroll
    for (int i = 0; i < 4; i++) mt[i] = fmaxf(s_[i][0], s_[i][1]);
#pragma unroll
    for (int o = 1; o < 16; o <<= 1)
#pragma unroll
      for (int i = 0; i < 4; i++) mt[i] = fmaxf(mt[i], __shfl_xor(mt[i], o));
#pragma unroll
    for (int i = 0; i < 4; i++) {
      int r = tr + 16 * i;
      float mo = m_l[r];
      float mn = fmaxf(mo, mt[i]);
      al[i] = (mo == -INFINITY) ? 0.f : __expf(mo - mn);
      float p0 = (s_[i][0] == -INFINITY) ? 0.f : __expf(s_[i][0] - mn);
      float p1 = (s_[i][1] == -INFINITY) ? 0.f : __expf(s_[i][1] - mn);
      s_[i][0] = p0; s_[i][1] = p1;
      lt[i] = p0 + p1;
      mt[i] = mn;
    }
#pragma unroll
    for (int o = 1; o < 16; o <<= 1)
#pragma unroll
      for (int i = 0; i < 4; i++) lt[i] += __shfl_xor(lt[i], o);
#pragma unroll
    for (int i = 0; i < 4; i++) {
      int r = tr + 16 * i;
      if (tc == 0) { m_l[r] = mt[i]; l_l[r] = al[i] * l_l[r] + lt[i]; }
#pragma unroll
      for (int j = 0; j < 4; j++) o_[i][j] *= al[i];
      Pt[r][tc] = s_[i][0];
      Pt[r][tc + 16] = s_[i][1];
    }
    // PV (Pt rows are wave-local: same-wave LDS ordering suffices, no barrier)
    for (int c = 0; c < 32; c += 4) {
      float4 pv[4], vv[4];
#pragma unroll
      for (int i = 0; i < 4; i++) pv[i] = *(float4*)&Pt[tr + 16 * i][c];
#pragma unroll
      for (int j = 0; j < 4; j++) vv[j] = *(float4*)&Vt[tc + 16 * j][c];
#pragma unroll
      for (int i = 0; i < 4; i++)
#pragma unroll
        for (int j = 0; j < 4; j++)
          o_[i][j] += pv[i].x * vv[j].x + pv[i].y * vv[j].y + pv[i].z * vv[j].z + pv[i].w * vv[j].w;
    }
  }
  __syncthreads();
#pragma unroll
  for (int i = 0; i < 4; i++) {
    int r = tr + 16 * i;
    float inv = 1.f / l_l[r];
#pragma unroll
    for (int j = 0; j < 4; j++) {
      int d = tc + 16 * j;
      ao[((size_t)(b * S_ + q0 + r)) * H_ + h * HD_ + d] = o_[i][j] * inv;
    }
  }
}

// ---------------------------------------------------------------------------
// k_resffn: x += ao@Wo + bo; ln2 over E=4; x += relu(ln2@Wf1+bf1)@Wf2 + bf2.
// One wave per token.
// ---------------------------------------------------------------------------
__global__ __launch_bounds__(256) void k_resffn(const float* __restrict__ ao,
                                                const float* __restrict__ Wo,
                                                const float* __restrict__ bo,
                                                const float* __restrict__ g2,
                                                const float* __restrict__ b2n,
                                                const float* __restrict__ Wf1,
                                                const float* __restrict__ bf1,
                                                const float* __restrict__ Wf2,
                                                const float* __restrict__ bf2,
                                                float* __restrict__ x) {
  int tok = blockIdx.x * 4 + (threadIdx.x >> 6);
  int lane = threadIdx.x & 63;
  const float* aor = ao + (size_t)tok * H_;
  float r0 = 0, r1 = 0, r2 = 0, r3 = 0;
#pragma unroll
  for (int k = 0; k < H_ / 64; k++) {
    int kk = lane + k * 64;
    float a = aor[kk];
    float4 w = *(const float4*)&Wo[kk * 4];
    r0 += a * w.x; r1 += a * w.y; r2 += a * w.z; r3 += a * w.w;
  }
#pragma unroll
  for (int o = 1; o < 64; o <<= 1) {
    r0 += __shfl_xor(r0, o); r1 += __shfl_xor(r1, o);
    r2 += __shfl_xor(r2, o); r3 += __shfl_xor(r3, o);
  }
  float4 xo = *(const float4*)&x[tok * 4];
  float x0 = xo.x + r0 + bo[0];
  float x1 = xo.y + r1 + bo[1];
  float x2 = xo.z + r2 + bo[2];
  float x3 = xo.w + r3 + bo[3];
  float mn = 0.25f * (x0 + x1 + x2 + x3);
  float d0 = x0 - mn, d1 = x1 - mn, d2 = x2 - mn, d3 = x3 - mn;
  float var = 0.25f * (d0 * d0 + d1 * d1 + d2 * d2 + d3 * d3);
  float rs = rsqrtf(var + EPS_);
  float l0 = d0 * rs * g2[0] + b2n[0];
  float l1 = d1 * rs * g2[1] + b2n[1];
  float l2 = d2 * rs * g2[2] + b2n[2];
  float l3 = d3 * rs * g2[3] + b2n[3];
  float f0 = 0, f1 = 0, f2 = 0, f3 = 0;
#pragma unroll
  for (int f4 = 0; f4 < FF_ / 64; f4++) {
    int f = lane + f4 * 64;
    float hh = bf1[f] + l0 * Wf1[f] + l1 * Wf1[FF_ + f] + l2 * Wf1[2 * FF_ + f] + l3 * Wf1[3 * FF_ + f];
    hh = fmaxf(hh, 0.f);
    float4 w2 = *(const float4*)&Wf2[f * 4];
    f0 += hh * w2.x; f1 += hh * w2.y; f2 += hh * w2.z; f3 += hh * w2.w;
  }
#pragma unroll
  for (int o = 1; o < 64; o <<= 1) {
    f0 += __shfl_xor(f0, o); f1 += __shfl_xor(f1, o);
    f2 += __shfl_xor(f2, o); f3 += __shfl_xor(f3, o);
  }
  x0 += f0 + bf2[0]; x1 += f1 + bf2[1]; x2 += f2 + bf2[2]; x3 += f3 + bf2[3];
  if (lane == 0) *(float4*)&x[tok * 4] = make_float4(x0, x1, x2, x3);
}

// ---------------------------------------------------------------------------
// k_out: out = x @ Wout + bout   (4096 x 4 x 17)
// ---------------------------------------------------------------------------
__global__ __launch_bounds__(256) void k_out(const float* __restrict__ x,
                                             const float* __restrict__ Wout,
                                             const float* __restrict__ bout,
                                             float* __restrict__ out) {
  int gid = blockIdx.x * 256 + threadIdx.x;
  if (gid >= BS_ * NT_) return;
  int tok = gid / NT_;
  int tt = gid - tok * NT_;
  float4 xr = ((const float4*)x)[tok];
  out[gid] = bout[tt] + xr.x * Wout[tt] + xr.y * Wout[NT_ + tt] + xr.z * Wout[2 * NT_ + tt] + xr.w * Wout[3 * NT_ + tt];
}

extern "C" void kernel_launch(void* const* d_in, const int* in_sizes, int n_in,
                              void* d_out, int out_size, void* d_ws, size_t ws_size,
                              hipStream_t stream) {
  const int* patches = (const int*)d_in[0];
  const int* mask = (const int*)d_in[1];
  const float* emb = (const float*)d_in[2];
  const float* Wi = (const float*)d_in[3];
  const float* bi = (const float*)d_in[4];
  const float* Wqkv = (const float*)d_in[5];
  const float* bqkv = (const float*)d_in[6];
  const float* Wo = (const float*)d_in[7];
  const float* bo = (const float*)d_in[8];
  const float* g1 = (const float*)d_in[9];
  const float* b1n = (const float*)d_in[10];
  const float* Wf1 = (const float*)d_in[11];
  const float* bf1 = (const float*)d_in[12];
  const float* Wf2 = (const float*)d_in[13];
  const float* bf2 = (const float*)d_in[14];
  const float* g2 = (const float*)d_in[15];
  const float* b2n = (const float*)d_in[16];
  const float* relemb = (const float*)d_in[17];
  const float* Wout = (const float*)d_in[18];
  const float* bout = (const float*)d_in[19];
  float* out = (float*)d_out;

  float* ws = (float*)d_ws;
  float* x = ws;                        // 16384
  float* xn = x + 16384;                // 2097152 (reused as attention output)
  float* qkv = xn + 2097152;            // 6291456
  float* biasum = qkv + 6291456;        // 252

  k_init<<<dim3(17), dim3(256), 0, stream>>>(patches, mask, emb, relemb, x, biasum);
  for (int l = 0; l < L_; l++) {
    k_inln<<<dim3(BS_), dim3(256), 0, stream>>>(x, Wi + l * E_ * H_, bi + l * H_,
                                                g1 + l * H_, b1n + l * H_, xn);
    k_qkv<<<dim3(12, 32), dim3(256), 0, stream>>>(xn, Wqkv + (size_t)l * H_ * 3 * H_,
                                                  bqkv + l * 3 * H_, qkv);
    k_attn<<<dim3(16, 8, 4), dim3(256), 0, stream>>>(qkv, mask, biasum + l * 63, xn);
    k_resffn<<<dim3(1024), dim3(256), 0, stream>>>(xn, Wo + l * H_ * E_, bo + l * E_,
                                                   g2 + l * E_, b2n + l * E_,
                                                   Wf1 + l * E_ * FF_, bf1 + l * FF_,
                                                   Wf2 + l * FF_ * E_, bf2 + l * E_, x);
  }
  k_out<<<dim3(272), dim3(256), 0, stream>>>(x, Wout, bout, out);
}

// Round 3
// 490.802 us; speedup vs baseline: 4.0857x; 4.0857x over previous
//
#include <hip/hip_runtime.h>
#include <hip/hip_bf16.h>
#include <math.h>

#define B_ 4
#define S_ 1024
#define H_ 512
#define NH_ 8
#define HD_ 64
#define FF_ 1024
#define E_ 4
#define L_ 4
#define NT_ 17
#define BS_ 4096
#define EPS_ 1e-5f
#define L2E_ 1.4426950408889634f
#define SCL_ 0.18033688011112042f   // 0.125 * log2(e)

typedef __attribute__((ext_vector_type(8))) short short8;
typedef __attribute__((ext_vector_type(16))) float f32x16;
typedef float float4u __attribute__((ext_vector_type(4), aligned(4)));

__device__ inline ushort bf16_rne(float f) {
  unsigned u = __builtin_bit_cast(unsigned, f);
  u += 0x7FFFu + ((u >> 16) & 1u);
  return (ushort)(u >> 16);
}
__device__ inline unsigned pk_bf16(float a, float b) {
  return (unsigned)bf16_rne(a) | ((unsigned)bf16_rne(b) << 16);
}

// ---------------------------------------------------------------------------
// k_init: x = emb[patches] (mask -> emb[16]); negT[b*S+k] = mask? -1e30 : 0;
// T[l][j] (j in [0,2112)) = biasum[l][clip(1086-j,0,62)] * log2(e)
// ---------------------------------------------------------------------------
__global__ __launch_bounds__(256) void k_init(const int* __restrict__ patches,
                                              const int* __restrict__ mask,
                                              const float* __restrict__ emb,
                                              const float* __restrict__ relemb,
                                              float* __restrict__ x,
                                              float* __restrict__ T,
                                              float* __restrict__ negT) {
  int gid = blockIdx.x * 256 + threadIdx.x;
  if (gid < BS_) {
    int mk = mask[gid];
    int row = mk ? (NT_ - 1) : patches[gid];
    ((float4*)x)[gid] = ((const float4*)emb)[row];
    negT[gid] = mk ? -1e30f : 0.f;
  } else {
    int idx = gid - BS_;
    if (idx < L_ * 2112) {
      int l = idx / 2112, j = idx - l * 2112;
      int c = 1086 - j;
      c = c < 0 ? 0 : (c > 62 ? 62 : c);
      const float* src = relemb + (size_t)(l * 63 + c) * 64;
      float s = 0.f;
#pragma unroll
      for (int d = 0; d < 64; d++) s += src[d];
      T[idx] = s * L2E_;
    }
  }
}

// ---------------------------------------------------------------------------
// k_cvtw: Wqkv fp32 [l][k=512][n=1536] -> Wt bf16 [l][n][k]  (transposed)
// ---------------------------------------------------------------------------
__global__ __launch_bounds__(256) void k_cvtw(const float* __restrict__ W,
                                              ushort* __restrict__ Wt) {
  int id = blockIdx.x * 256 + threadIdx.x;  // total L*64*1536
  int n = id % 1536;
  int r = id / 1536;           // l*64 + kc
  int kc = r & 63, l = r >> 6;
  const float* src = W + (size_t)l * 512 * 1536 + n;
  ushort* dst = Wt + ((size_t)(l * 1536 + n)) * 512 + kc * 8;
  uint4 o;
  o.x = pk_bf16(src[(size_t)(kc * 8 + 0) * 1536], src[(size_t)(kc * 8 + 1) * 1536]);
  o.y = pk_bf16(src[(size_t)(kc * 8 + 2) * 1536], src[(size_t)(kc * 8 + 3) * 1536]);
  o.z = pk_bf16(src[(size_t)(kc * 8 + 4) * 1536], src[(size_t)(kc * 8 + 5) * 1536]);
  o.w = pk_bf16(src[(size_t)(kc * 8 + 6) * 1536], src[(size_t)(kc * 8 + 7) * 1536]);
  *(uint4*)dst = o;
}

// ---------------------------------------------------------------------------
// k_inln: xp = x @ Wi + bi ; xn = layernorm(xp)*g1 + b1n -> bf16. Block/token.
// ---------------------------------------------------------------------------
__global__ __launch_bounds__(256) void k_inln(const float* __restrict__ x,
                                              const float* __restrict__ Wi,
                                              const float* __restrict__ bi,
                                              const float* __restrict__ g1,
                                              const float* __restrict__ b1n,
                                              ushort* __restrict__ xnbf) {
  __shared__ float red_s[4], red_q[4];
  int tok = blockIdx.x;
  int t = threadIdx.x;
  float4 xr = ((const float4*)x)[tok];
  int j0 = 2 * t, j1 = 2 * t + 1;
  float xp0 = bi[j0] + xr.x * Wi[j0] + xr.y * Wi[H_ + j0] + xr.z * Wi[2 * H_ + j0] + xr.w * Wi[3 * H_ + j0];
  float xp1 = bi[j1] + xr.x * Wi[j1] + xr.y * Wi[H_ + j1] + xr.z * Wi[2 * H_ + j1] + xr.w * Wi[3 * H_ + j1];
  float s = xp0 + xp1;
  float q = xp0 * xp0 + xp1 * xp1;
#pragma unroll
  for (int o = 32; o > 0; o >>= 1) {
    s += __shfl_xor(s, o);
    q += __shfl_xor(q, o);
  }
  int wid = t >> 6;
  if ((t & 63) == 0) { red_s[wid] = s; red_q[wid] = q; }
  __syncthreads();
  s = red_s[0] + red_s[1] + red_s[2] + red_s[3];
  q = red_q[0] + red_q[1] + red_q[2] + red_q[3];
  float mean = s * (1.f / (float)H_);
  float var = q * (1.f / (float)H_) - mean * mean;
  float rs = rsqrtf(var + EPS_);
  float v0 = (xp0 - mean) * rs * g1[j0] + b1n[j0];
  float v1 = (xp1 - mean) * rs * g1[j1] + b1n[j1];
  ((unsigned*)xnbf)[tok * 256 + t] = pk_bf16(v0, v1);
}

// ---------------------------------------------------------------------------
// k_qkv: bf16 MFMA GEMM  C(4096x1536) = xn(4096x512) @ Wqkv + bias.
// 128x128 tile, BK=64, 4 waves each 64x64 (2x2 of 32x32 MFMA tiles).
// q/k blocks (n0<1024): operand-swapped -> C^T, lane holds one token ->
//   packed 8B stores to q_bf/k_bf [b][h][s][d].  v blocks: normal -> lane
//   holds one d -> packed 8B stores to vT [b][h][d][s].
// ---------------------------------------------------------------------------
__global__ __launch_bounds__(256) void k_qkv(const ushort* __restrict__ A,
                                             const ushort* __restrict__ Wt,
                                             const float* __restrict__ bias,
                                             ushort* __restrict__ qbf,
                                             ushort* __restrict__ kbf,
                                             ushort* __restrict__ vTb) {
  __shared__ ushort At[128][72];
  __shared__ ushort Bt[128][72];
  int t = threadIdx.x;
  int n0 = blockIdx.x * 128, m0 = blockIdx.y * 128;
  bool tr = (n0 < 1024);
  int w = t >> 6, lq = t & 31, hh = (t >> 5) & 1;
  int wm = (w & 1) * 64, wn = (w >> 1) * 64;
  f32x16 acc[2][2];
#pragma unroll
  for (int mt = 0; mt < 2; mt++)
#pragma unroll
    for (int nt = 0; nt < 2; nt++)
#pragma unroll
      for (int i = 0; i < 16; i++) acc[mt][nt][i] = 0.f;

  for (int k0 = 0; k0 < 512; k0 += 64) {
    __syncthreads();
#pragma unroll
    for (int j = 0; j < 4; j++) {
      int id = 256 * j + t;
      int row = id >> 3, u = id & 7;
      *(uint4*)&At[row][u * 8] = *(const uint4*)(A + (size_t)(m0 + row) * 512 + k0 + u * 8);
      *(uint4*)&Bt[row][u * 8] = *(const uint4*)(Wt + (size_t)(n0 + row) * 512 + k0 + u * 8);
    }
    __syncthreads();
#pragma unroll
    for (int kc = 0; kc < 4; kc++) {
      short8 af[2], bf[2];
#pragma unroll
      for (int mt = 0; mt < 2; mt++) af[mt] = *(const short8*)&At[wm + mt * 32 + lq][kc * 16 + hh * 8];
#pragma unroll
      for (int nt = 0; nt < 2; nt++) bf[nt] = *(const short8*)&Bt[wn + nt * 32 + lq][kc * 16 + hh * 8];
#pragma unroll
      for (int mt = 0; mt < 2; mt++)
#pragma unroll
        for (int nt = 0; nt < 2; nt++) {
          if (tr)
            acc[mt][nt] = __builtin_amdgcn_mfma_f32_32x32x16_bf16(bf[nt], af[mt], acc[mt][nt], 0, 0, 0);
          else
            acc[mt][nt] = __builtin_amdgcn_mfma_f32_32x32x16_bf16(af[mt], bf[nt], acc[mt][nt], 0, 0, 0);
        }
    }
  }

  if (tr) {
    // C^T: col = token = m0+wm+mt*32+lq ; row = n-local = i+8*rg+4*hh (+nt*32)
#pragma unroll
    for (int mt = 0; mt < 2; mt++) {
      int token = m0 + wm + mt * 32 + lq;
      int bb = token >> 10, sr = token & 1023;
#pragma unroll
      for (int nt = 0; nt < 2; nt++) {
        int nn = n0 + wn + nt * 32;
        int nloc = (nn < 512) ? nn : nn - 512;
        ushort* dst = (nn < 512) ? qbf : kbf;
        int hd = nloc >> 6;
        size_t rowbase = ((size_t)(bb * 8 + hd) * 1024 + sr) * 64;
#pragma unroll
        for (int rg = 0; rg < 4; rg++) {
          int nbase = nn + rg * 8 + hh * 4;
          float4 bv = *(const float4*)(bias + nbase);
          float v0 = acc[mt][nt][rg * 4 + 0] + bv.x;
          float v1 = acc[mt][nt][rg * 4 + 1] + bv.y;
          float v2 = acc[mt][nt][rg * 4 + 2] + bv.z;
          float v3 = acc[mt][nt][rg * 4 + 3] + bv.w;
          int d0 = (nloc & 63) + rg * 8 + hh * 4;
          *(uint2*)(dst + rowbase + d0) = make_uint2(pk_bf16(v0, v1), pk_bf16(v2, v3));
        }
      }
    }
  } else {
    // normal: col = n (lane) -> fixed d ; rows = tokens in runs of 4
#pragma unroll
    for (int nt = 0; nt < 2; nt++) {
      int n = n0 + wn + nt * 32 + lq;
      int nloc = n - 1024;
      int hd = nloc >> 6, d = nloc & 63;
      float bb_ = bias[n];
#pragma unroll
      for (int mt = 0; mt < 2; mt++) {
#pragma unroll
        for (int rg = 0; rg < 4; rg++) {
          int tb = m0 + wm + mt * 32 + rg * 8 + hh * 4;
          int bb = tb >> 10, sr = tb & 1023;
          float v0 = acc[mt][nt][rg * 4 + 0] + bb_;
          float v1 = acc[mt][nt][rg * 4 + 1] + bb_;
          float v2 = acc[mt][nt][rg * 4 + 2] + bb_;
          float v3 = acc[mt][nt][rg * 4 + 3] + bb_;
          *(uint2*)(vTb + ((size_t)(bb * 8 + hd) * 64 + d) * 1024 + sr) =
              make_uint2(pk_bf16(v0, v1), pk_bf16(v2, v3));
        }
      }
    }
  }
}

// ---------------------------------------------------------------------------
// k_attn: bf16 MFMA flash attention, S^T formulation.
// 1 wave / block, 32 q per wave (q = col = lane&31), keys tiled by 64.
// S^T = K·Q^T  (lane-local softmax);  O^T = V^T·P  (lane-local alpha).
// log2-domain softmax; bias via reversed-Toeplitz table T (pre *log2e).
// ---------------------------------------------------------------------------
__global__ __launch_bounds__(64) void k_attn(const ushort* __restrict__ qbf,
                                             const ushort* __restrict__ kbf,
                                             const ushort* __restrict__ vTb,
                                             const float* __restrict__ Tl,
                                             const float* __restrict__ negT,
                                             float* __restrict__ ao) {
  __shared__ ushort Pt[32][72];
  int lane = threadIdx.x;
  int lq = lane & 31, hh = lane >> 5;
  int qb = blockIdx.x * 32;
  int head = blockIdx.y, b = blockIdx.z;
  int bh = b * NH_ + head;
  int q = qb + lq;

  const ushort* qrow = qbf + ((size_t)(bh * S_ + q)) * 64;
  short8 Qf[4];
#pragma unroll
  for (int c = 0; c < 4; c++) Qf[c] = *(const short8*)(qrow + c * 16 + hh * 8);

  float m_run = -INFINITY, l_run = 0.f;
  f32x16 Ot[2];
#pragma unroll
  for (int dt = 0; dt < 2; dt++)
#pragma unroll
    for (int i = 0; i < 16; i++) Ot[dt][i] = 0.f;

  for (int k0 = 0; k0 < S_; k0 += 64) {
    // ---- S^T tiles: rows = keys, cols = q ----
    f32x16 sa[2];
#pragma unroll
    for (int st = 0; st < 2; st++) {
      const ushort* krow = kbf + ((size_t)(bh * S_ + k0 + st * 32 + lq)) * 64;
      f32x16 a;
#pragma unroll
      for (int i = 0; i < 16; i++) a[i] = 0.f;
#pragma unroll
      for (int c = 0; c < 4; c++) {
        short8 Kf = *(const short8*)(krow + c * 16 + hh * 8);
        a = __builtin_amdgcn_mfma_f32_32x32x16_bf16(Kf, Qf[c], a, 0, 0, 0);
      }
      sa[st] = a;
    }
    // ---- bias + mask + collect (log2 domain) ----
    float sv[32];
    float mloc = -INFINITY;
#pragma unroll
    for (int st = 0; st < 2; st++)
#pragma unroll
      for (int rg = 0; rg < 4; rg++) {
        int krun = k0 + st * 32 + rg * 8 + hh * 4;
        float4u bv = *(const float4u*)(Tl + (krun - q + 31 + 1024));
        float4 nv = *(const float4*)(negT + b * S_ + krun);
#pragma unroll
        for (int i = 0; i < 4; i++) {
          float bvi = bv[i];
          float nvi = (i == 0) ? nv.x : (i == 1) ? nv.y : (i == 2) ? nv.z : nv.w;
          float t0 = (krun + i == q) ? bvi : (bvi + nvi);
          float s = fmaf(sa[st][rg * 4 + i], SCL_, t0);
          sv[st * 16 + rg * 4 + i] = s;
          mloc = fmaxf(mloc, s);
        }
      }
    float mx = fmaxf(mloc, __shfl_xor(mloc, 32));
    float mnew = fmaxf(m_run, mx);
    float alpha = exp2f(m_run - mnew);  // first iter: exp2(-inf)=0
    // ---- p = exp2(sv - mnew), pack bf16 to LDS, lane-local row sum ----
    float lsum = 0.f;
#pragma unroll
    for (int st = 0; st < 2; st++)
#pragma unroll
      for (int rg = 0; rg < 4; rg++) {
        float p0 = exp2f(sv[st * 16 + rg * 4 + 0] - mnew);
        float p1 = exp2f(sv[st * 16 + rg * 4 + 1] - mnew);
        float p2 = exp2f(sv[st * 16 + rg * 4 + 2] - mnew);
        float p3 = exp2f(sv[st * 16 + rg * 4 + 3] - mnew);
        lsum += (p0 + p1) + (p2 + p3);
        *(uint2*)&Pt[lq][st * 32 + rg * 8 + hh * 4] = make_uint2(pk_bf16(p0, p1), pk_bf16(p2, p3));
      }
    lsum += __shfl_xor(lsum, 32);
    l_run = l_run * alpha + lsum;
    m_run = mnew;
#pragma unroll
    for (int dt = 0; dt < 2; dt++)
#pragma unroll
      for (int i = 0; i < 16; i++) Ot[dt][i] *= alpha;
    // ---- O^T += V^T · P ----
    short8 Pf[4];
#pragma unroll
    for (int c = 0; c < 4; c++) Pf[c] = *(const short8*)&Pt[lq][c * 16 + hh * 8];
#pragma unroll
    for (int dt = 0; dt < 2; dt++) {
      const ushort* vrow = vTb + ((size_t)(bh * 64 + dt * 32 + lq)) * S_ + k0;
#pragma unroll
      for (int c = 0; c < 4; c++) {
        short8 Vf = *(const short8*)(vrow + c * 16 + hh * 8);
        Ot[dt] = __builtin_amdgcn_mfma_f32_32x32x16_bf16(Vf, Pf[c], Ot[dt], 0, 0, 0);
      }
    }
  }
  // ---- epilogue: lane holds col q; rows d = i+8*rg+4*hh (+32*dt) ----
  float inv = 1.f / l_run;
  float* aorow = ao + ((size_t)(b * S_ + q)) * H_ + head * 64;
#pragma unroll
  for (int dt = 0; dt < 2; dt++)
#pragma unroll
    for (int rg = 0; rg < 4; rg++) {
      float4 o = make_float4(Ot[dt][rg * 4 + 0] * inv, Ot[dt][rg * 4 + 1] * inv,
                             Ot[dt][rg * 4 + 2] * inv, Ot[dt][rg * 4 + 3] * inv);
      *(float4*)(aorow + dt * 32 + rg * 8 + hh * 4) = o;
    }
}

// ---------------------------------------------------------------------------
// k_resffn: x += ao@Wo + bo; ln2 over E=4; x += relu(ln2@Wf1+bf1)@Wf2 + bf2.
// One wave per token.
// ---------------------------------------------------------------------------
__global__ __launch_bounds__(256) void k_resffn(const float* __restrict__ ao,
                                                const float* __restrict__ Wo,
                                                const float* __restrict__ bo,
                                                const float* __restrict__ g2,
                                                const float* __restrict__ b2n,
                                                const float* __restrict__ Wf1,
                                                const float* __restrict__ bf1,
                                                const float* __restrict__ Wf2,
                                                const float* __restrict__ bf2,
                                                float* __restrict__ x) {
  int tok = blockIdx.x * 4 + (threadIdx.x >> 6);
  int lane = threadIdx.x & 63;
  const float* aor = ao + (size_t)tok * H_;
  float r0 = 0, r1 = 0, r2 = 0, r3 = 0;
#pragma unroll
  for (int k = 0; k < H_ / 64; k++) {
    int kk = lane + k * 64;
    float a = aor[kk];
    float4 w = *(const float4*)&Wo[kk * 4];
    r0 += a * w.x; r1 += a * w.y; r2 += a * w.z; r3 += a * w.w;
  }
#pragma unroll
  for (int o = 1; o < 64; o <<= 1) {
    r0 += __shfl_xor(r0, o); r1 += __shfl_xor(r1, o);
    r2 += __shfl_xor(r2, o); r3 += __shfl_xor(r3, o);
  }
  float4 xo = *(const float4*)&x[tok * 4];
  float x0 = xo.x + r0 + bo[0];
  float x1 = xo.y + r1 + bo[1];
  float x2 = xo.z + r2 + bo[2];
  float x3 = xo.w + r3 + bo[3];
  float mn = 0.25f * (x0 + x1 + x2 + x3);
  float d0 = x0 - mn, d1 = x1 - mn, d2 = x2 - mn, d3 = x3 - mn;
  float var = 0.25f * (d0 * d0 + d1 * d1 + d2 * d2 + d3 * d3);
  float rs = rsqrtf(var + EPS_);
  float l0 = d0 * rs * g2[0] + b2n[0];
  float l1 = d1 * rs * g2[1] + b2n[1];
  float l2 = d2 * rs * g2[2] + b2n[2];
  float l3 = d3 * rs * g2[3] + b2n[3];
  float f0 = 0, f1 = 0, f2 = 0, f3 = 0;
#pragma unroll
  for (int f4 = 0; f4 < FF_ / 64; f4++) {
    int f = lane + f4 * 64;
    float hh = bf1[f] + l0 * Wf1[f] + l1 * Wf1[FF_ + f] + l2 * Wf1[2 * FF_ + f] + l3 * Wf1[3 * FF_ + f];
    hh = fmaxf(hh, 0.f);
    float4 w2 = *(const float4*)&Wf2[f * 4];
    f0 += hh * w2.x; f1 += hh * w2.y; f2 += hh * w2.z; f3 += hh * w2.w;
  }
#pragma unroll
  for (int o = 1; o < 64; o <<= 1) {
    f0 += __shfl_xor(f0, o); f1 += __shfl_xor(f1, o);
    f2 += __shfl_xor(f2, o); f3 += __shfl_xor(f3, o);
  }
  x0 += f0 + bf2[0]; x1 += f1 + bf2[1]; x2 += f2 + bf2[2]; x3 += f3 + bf2[3];
  if (lane == 0) *(float4*)&x[tok * 4] = make_float4(x0, x1, x2, x3);
}

// ---------------------------------------------------------------------------
// k_out: out = x @ Wout + bout   (4096 x 4 x 17)
// ---------------------------------------------------------------------------
__global__ __launch_bounds__(256) void k_out(const float* __restrict__ x,
                                             const float* __restrict__ Wout,
                                             const float* __restrict__ bout,
                                             float* __restrict__ out) {
  int gid = blockIdx.x * 256 + threadIdx.x;
  if (gid >= BS_ * NT_) return;
  int tok = gid / NT_;
  int tt = gid - tok * NT_;
  float4 xr = ((const float4*)x)[tok];
  out[gid] = bout[tt] + xr.x * Wout[tt] + xr.y * Wout[NT_ + tt] + xr.z * Wout[2 * NT_ + tt] + xr.w * Wout[3 * NT_ + tt];
}

extern "C" void kernel_launch(void* const* d_in, const int* in_sizes, int n_in,
                              void* d_out, int out_size, void* d_ws, size_t ws_size,
                              hipStream_t stream) {
  const int* patches = (const int*)d_in[0];
  const int* mask = (const int*)d_in[1];
  const float* emb = (const float*)d_in[2];
  const float* Wi = (const float*)d_in[3];
  const float* bi = (const float*)d_in[4];
  const float* Wqkv = (const float*)d_in[5];
  const float* bqkv = (const float*)d_in[6];
  const float* Wo = (const float*)d_in[7];
  const float* bo = (const float*)d_in[8];
  const float* g1 = (const float*)d_in[9];
  const float* b1n = (const float*)d_in[10];
  const float* Wf1 = (const float*)d_in[11];
  const float* bf1 = (const float*)d_in[12];
  const float* Wf2 = (const float*)d_in[13];
  const float* bf2 = (const float*)d_in[14];
  const float* g2 = (const float*)d_in[15];
  const float* b2n = (const float*)d_in[16];
  const float* relemb = (const float*)d_in[17];
  const float* Wout = (const float*)d_in[18];
  const float* bout = (const float*)d_in[19];
  float* out = (float*)d_out;

  char* p = (char*)d_ws;
  float* x = (float*)p;          p += (size_t)BS_ * 4 * 4;
  float* T = (float*)p;          p += (size_t)L_ * 2112 * 4;
  float* negT = (float*)p;       p += (size_t)BS_ * 4;
  float* ao = (float*)p;         p += (size_t)BS_ * H_ * 4;
  ushort* xnbf = (ushort*)p;     p += (size_t)BS_ * H_ * 2;
  ushort* Wt = (ushort*)p;       p += (size_t)L_ * 1536 * 512 * 2;
  ushort* qbf = (ushort*)p;      p += (size_t)32 * 1024 * 64 * 2;
  ushort* kbf = (ushort*)p;      p += (size_t)32 * 1024 * 64 * 2;
  ushort* vTb = (ushort*)p;      p += (size_t)32 * 64 * 1024 * 2;

  k_init<<<dim3(49), dim3(256), 0, stream>>>(patches, mask, emb, relemb, x, T, negT);
  k_cvtw<<<dim3(1536), dim3(256), 0, stream>>>(Wqkv, Wt);
  for (int l = 0; l < L_; l++) {
    k_inln<<<dim3(BS_), dim3(256), 0, stream>>>(x, Wi + l * E_ * H_, bi + l * H_,
                                                g1 + l * H_, b1n + l * H_, xnbf);
    k_qkv<<<dim3(12, 32), dim3(256), 0, stream>>>(xnbf, Wt + (size_t)l * 1536 * 512,
                                                  bqkv + l * 3 * H_, qbf, kbf, vTb);
    k_attn<<<dim3(32, 8, 4), dim3(64), 0, stream>>>(qbf, kbf, vTb, T + l * 2112, negT, ao);
    k_resffn<<<dim3(1024), dim3(256), 0, stream>>>(ao, Wo + l * H_ * E_, bo + l * E_,
                                                   g2 + l * E_, b2n + l * E_,
                                                   Wf1 + l * E_ * FF_, bf1 + l * FF_,
                                                   Wf2 + l * FF_ * E_, bf2 + l * E_, x);
  }
  k_out<<<dim3(272), dim3(256), 0, stream>>>(x, Wout, bout, out);
}

// Round 4
// 421.897 us; speedup vs baseline: 4.7530x; 1.1633x over previous
//
#include <hip/hip_runtime.h>
#include <hip/hip_bf16.h>
#include <math.h>

#define B_ 4
#define S_ 1024
#define H_ 512
#define NH_ 8
#define HD_ 64
#define FF_ 1024
#define E_ 4
#define L_ 4
#define NT_ 17
#define BS_ 4096
#define EPS_ 1e-5f
#define L2E_ 1.4426950408889634f
#define SCL_ 0.18033688011112042f   // 0.125 * log2(e)

typedef __attribute__((ext_vector_type(8))) short short8;
typedef __attribute__((ext_vector_type(16))) float f32x16;
typedef float float4u __attribute__((ext_vector_type(4), aligned(4)));

__device__ inline ushort bf16_rne(float f) {
  unsigned u = __builtin_bit_cast(unsigned, f);
  u += 0x7FFFu + ((u >> 16) & 1u);
  return (ushort)(u >> 16);
}
__device__ inline unsigned pk_bf16(float a, float b) {
  return (unsigned)bf16_rne(a) | ((unsigned)bf16_rne(b) << 16);
}

// ---------------------------------------------------------------------------
// k_init: x = emb[patches] (mask -> emb[16]); negT[b*S+k] = mask? -1e30 : 0;
// T[l][j] (j in [0,2112)) = biasum[l][clip(1086-j,0,62)] * log2(e)
// ---------------------------------------------------------------------------
__global__ __launch_bounds__(256) void k_init(const int* __restrict__ patches,
                                              const int* __restrict__ mask,
                                              const float* __restrict__ emb,
                                              const float* __restrict__ relemb,
                                              float* __restrict__ x,
                                              float* __restrict__ T,
                                              float* __restrict__ negT) {
  int gid = blockIdx.x * 256 + threadIdx.x;
  if (gid < BS_) {
    int mk = mask[gid];
    int row = mk ? (NT_ - 1) : patches[gid];
    ((float4*)x)[gid] = ((const float4*)emb)[row];
    negT[gid] = mk ? -1e30f : 0.f;
  } else {
    int idx = gid - BS_;
    if (idx < L_ * 2112) {
      int l = idx / 2112, j = idx - l * 2112;
      int c = 1086 - j;
      c = c < 0 ? 0 : (c > 62 ? 62 : c);
      const float* src = relemb + (size_t)(l * 63 + c) * 64;
      float s = 0.f;
#pragma unroll
      for (int d = 0; d < 64; d++) s += src[d];
      T[idx] = s * L2E_;
    }
  }
}

// ---------------------------------------------------------------------------
// k_cvtw: Wqkv fp32 [l][k=512][n=1536] -> Wt bf16 [l][n][k]  (transposed)
// ---------------------------------------------------------------------------
__global__ __launch_bounds__(256) void k_cvtw(const float* __restrict__ W,
                                              ushort* __restrict__ Wt) {
  int id = blockIdx.x * 256 + threadIdx.x;  // total L*64*1536
  int n = id % 1536;
  int r = id / 1536;           // l*64 + kc
  int kc = r & 63, l = r >> 6;
  const float* src = W + (size_t)l * 512 * 1536 + n;
  ushort* dst = Wt + ((size_t)(l * 1536 + n)) * 512 + kc * 8;
  uint4 o;
  o.x = pk_bf16(src[(size_t)(kc * 8 + 0) * 1536], src[(size_t)(kc * 8 + 1) * 1536]);
  o.y = pk_bf16(src[(size_t)(kc * 8 + 2) * 1536], src[(size_t)(kc * 8 + 3) * 1536]);
  o.z = pk_bf16(src[(size_t)(kc * 8 + 4) * 1536], src[(size_t)(kc * 8 + 5) * 1536]);
  o.w = pk_bf16(src[(size_t)(kc * 8 + 6) * 1536], src[(size_t)(kc * 8 + 7) * 1536]);
  *(uint4*)dst = o;
}

// ---------------------------------------------------------------------------
// k_inln: xp = x @ Wi + bi ; xn = layernorm(xp)*g1 + b1n -> bf16. Block/token.
// ---------------------------------------------------------------------------
__global__ __launch_bounds__(256) void k_inln(const float* __restrict__ x,
                                              const float* __restrict__ Wi,
                                              const float* __restrict__ bi,
                                              const float* __restrict__ g1,
                                              const float* __restrict__ b1n,
                                              ushort* __restrict__ xnbf) {
  __shared__ float red_s[4], red_q[4];
  int tok = blockIdx.x;
  int t = threadIdx.x;
  float4 xr = ((const float4*)x)[tok];
  int j0 = 2 * t, j1 = 2 * t + 1;
  float xp0 = bi[j0] + xr.x * Wi[j0] + xr.y * Wi[H_ + j0] + xr.z * Wi[2 * H_ + j0] + xr.w * Wi[3 * H_ + j0];
  float xp1 = bi[j1] + xr.x * Wi[j1] + xr.y * Wi[H_ + j1] + xr.z * Wi[2 * H_ + j1] + xr.w * Wi[3 * H_ + j1];
  float s = xp0 + xp1;
  float q = xp0 * xp0 + xp1 * xp1;
#pragma unroll
  for (int o = 32; o > 0; o >>= 1) {
    s += __shfl_xor(s, o);
    q += __shfl_xor(q, o);
  }
  int wid = t >> 6;
  if ((t & 63) == 0) { red_s[wid] = s; red_q[wid] = q; }
  __syncthreads();
  s = red_s[0] + red_s[1] + red_s[2] + red_s[3];
  q = red_q[0] + red_q[1] + red_q[2] + red_q[3];
  float mean = s * (1.f / (float)H_);
  float var = q * (1.f / (float)H_) - mean * mean;
  float rs = rsqrtf(var + EPS_);
  float v0 = (xp0 - mean) * rs * g1[j0] + b1n[j0];
  float v1 = (xp1 - mean) * rs * g1[j1] + b1n[j1];
  ((unsigned*)xnbf)[tok * 256 + t] = pk_bf16(v0, v1);
}

// ---------------------------------------------------------------------------
// k_qkv: bf16 MFMA GEMM  C(4096x1536) = xn(4096x512) @ Wqkv + bias.
// 128x128 tile, BK=64, 4 waves each 64x64 (2x2 of 32x32 MFMA tiles).
// ---------------------------------------------------------------------------
__global__ __launch_bounds__(256) void k_qkv(const ushort* __restrict__ A,
                                             const ushort* __restrict__ Wt,
                                             const float* __restrict__ bias,
                                             ushort* __restrict__ qbf,
                                             ushort* __restrict__ kbf,
                                             ushort* __restrict__ vTb) {
  __shared__ ushort At[128][72];
  __shared__ ushort Bt[128][72];
  int t = threadIdx.x;
  int n0 = blockIdx.x * 128, m0 = blockIdx.y * 128;
  bool tr = (n0 < 1024);
  int w = t >> 6, lq = t & 31, hh = (t >> 5) & 1;
  int wm = (w & 1) * 64, wn = (w >> 1) * 64;
  f32x16 acc[2][2];
#pragma unroll
  for (int mt = 0; mt < 2; mt++)
#pragma unroll
    for (int nt = 0; nt < 2; nt++)
#pragma unroll
      for (int i = 0; i < 16; i++) acc[mt][nt][i] = 0.f;

  for (int k0 = 0; k0 < 512; k0 += 64) {
    __syncthreads();
#pragma unroll
    for (int j = 0; j < 4; j++) {
      int id = 256 * j + t;
      int row = id >> 3, u = id & 7;
      *(uint4*)&At[row][u * 8] = *(const uint4*)(A + (size_t)(m0 + row) * 512 + k0 + u * 8);
      *(uint4*)&Bt[row][u * 8] = *(const uint4*)(Wt + (size_t)(n0 + row) * 512 + k0 + u * 8);
    }
    __syncthreads();
#pragma unroll
    for (int kc = 0; kc < 4; kc++) {
      short8 af[2], bf[2];
#pragma unroll
      for (int mt = 0; mt < 2; mt++) af[mt] = *(const short8*)&At[wm + mt * 32 + lq][kc * 16 + hh * 8];
#pragma unroll
      for (int nt = 0; nt < 2; nt++) bf[nt] = *(const short8*)&Bt[wn + nt * 32 + lq][kc * 16 + hh * 8];
#pragma unroll
      for (int mt = 0; mt < 2; mt++)
#pragma unroll
        for (int nt = 0; nt < 2; nt++) {
          if (tr)
            acc[mt][nt] = __builtin_amdgcn_mfma_f32_32x32x16_bf16(bf[nt], af[mt], acc[mt][nt], 0, 0, 0);
          else
            acc[mt][nt] = __builtin_amdgcn_mfma_f32_32x32x16_bf16(af[mt], bf[nt], acc[mt][nt], 0, 0, 0);
        }
    }
  }

  if (tr) {
#pragma unroll
    for (int mt = 0; mt < 2; mt++) {
      int token = m0 + wm + mt * 32 + lq;
      int bb = token >> 10, sr = token & 1023;
#pragma unroll
      for (int nt = 0; nt < 2; nt++) {
        int nn = n0 + wn + nt * 32;
        int nloc = (nn < 512) ? nn : nn - 512;
        ushort* dst = (nn < 512) ? qbf : kbf;
        int hd = nloc >> 6;
        size_t rowbase = ((size_t)(bb * 8 + hd) * 1024 + sr) * 64;
#pragma unroll
        for (int rg = 0; rg < 4; rg++) {
          int nbase = nn + rg * 8 + hh * 4;
          float4 bv = *(const float4*)(bias + nbase);
          float v0 = acc[mt][nt][rg * 4 + 0] + bv.x;
          float v1 = acc[mt][nt][rg * 4 + 1] + bv.y;
          float v2 = acc[mt][nt][rg * 4 + 2] + bv.z;
          float v3 = acc[mt][nt][rg * 4 + 3] + bv.w;
          int d0 = (nloc & 63) + rg * 8 + hh * 4;
          *(uint2*)(dst + rowbase + d0) = make_uint2(pk_bf16(v0, v1), pk_bf16(v2, v3));
        }
      }
    }
  } else {
#pragma unroll
    for (int nt = 0; nt < 2; nt++) {
      int n = n0 + wn + nt * 32 + lq;
      int nloc = n - 1024;
      int hd = nloc >> 6, d = nloc & 63;
      float bb_ = bias[n];
#pragma unroll
      for (int mt = 0; mt < 2; mt++) {
#pragma unroll
        for (int rg = 0; rg < 4; rg++) {
          int tb = m0 + wm + mt * 32 + rg * 8 + hh * 4;
          int bb = tb >> 10, sr = tb & 1023;
          float v0 = acc[mt][nt][rg * 4 + 0] + bb_;
          float v1 = acc[mt][nt][rg * 4 + 1] + bb_;
          float v2 = acc[mt][nt][rg * 4 + 2] + bb_;
          float v3 = acc[mt][nt][rg * 4 + 3] + bb_;
          *(uint2*)(vTb + ((size_t)(bb * 8 + hd) * 64 + d) * 1024 + sr) =
              make_uint2(pk_bf16(v0, v1), pk_bf16(v2, v3));
        }
      }
    }
  }
}

// ---------------------------------------------------------------------------
// k_attn: bf16 MFMA flash attention, S^T formulation, 4 waves/block.
// Block = (b, h, 128 q).  K/V tiles (64 keys) double-buffered in LDS, shared
// by all 4 waves; global->reg prefetch of tile t+1 overlaps compute of t.
// Per wave: 32 q (q = col = lane&31).  S^T = K.Q^T (lane-local softmax);
// O^T = V^T.P (lane-local alpha).  log2-domain softmax.
// ---------------------------------------------------------------------------
__global__ __launch_bounds__(256) void k_attn(const ushort* __restrict__ qbf,
                                              const ushort* __restrict__ kbf,
                                              const ushort* __restrict__ vTb,
                                              const float* __restrict__ Tl,
                                              const float* __restrict__ negT,
                                              float* __restrict__ ao) {
  __shared__ ushort Kt[2][64][72];
  __shared__ ushort Vt[2][64][72];
  __shared__ ushort Pt[4][32][72];
  int t = threadIdx.x;
  int w = t >> 6, lane = t & 63;
  int lq = lane & 31, hh = lane >> 5;
  int head = blockIdx.y, b = blockIdx.z;
  int bh = b * NH_ + head;
  int q = blockIdx.x * 128 + w * 32 + lq;

  const ushort* qrow = qbf + ((size_t)(bh * S_ + q)) * 64;
  short8 Qf[4];
#pragma unroll
  for (int c = 0; c < 4; c++) Qf[c] = *(const short8*)(qrow + c * 16 + hh * 8);

  // staging indices: thread covers chunks t and t+256 of the 512-chunk tile
  int srow0 = t >> 3, scol = (t & 7) * 8;
  const ushort* kbase = kbf + (size_t)bh * S_ * 64;
  const ushort* vbase = vTb + (size_t)bh * 64 * S_;

  uint4 kr0, kr1, vr0, vr1;
#define LOADREGS(k0_)                                                        \
  kr0 = *(const uint4*)(kbase + (size_t)((k0_) + srow0) * 64 + scol);        \
  kr1 = *(const uint4*)(kbase + (size_t)((k0_) + srow0 + 32) * 64 + scol);   \
  vr0 = *(const uint4*)(vbase + (size_t)srow0 * S_ + (k0_) + scol);         \
  vr1 = *(const uint4*)(vbase + (size_t)(srow0 + 32) * S_ + (k0_) + scol);
#define WRITELDS(buf_)                                                       \
  *(uint4*)&Kt[buf_][srow0][scol] = kr0;                                     \
  *(uint4*)&Kt[buf_][srow0 + 32][scol] = kr1;                                \
  *(uint4*)&Vt[buf_][srow0][scol] = vr0;                                     \
  *(uint4*)&Vt[buf_][srow0 + 32][scol] = vr1;

  float m_run = -INFINITY, l_run = 0.f;
  f32x16 Ot[2];
#pragma unroll
  for (int dt = 0; dt < 2; dt++)
#pragma unroll
    for (int i = 0; i < 16; i++) Ot[dt][i] = 0.f;

  LOADREGS(0);
  WRITELDS(0);
  __syncthreads();

  for (int it = 0; it < 16; it++) {
    int buf = it & 1;
    int k0 = it * 64;
    if (it < 15) { LOADREGS(k0 + 64); }
    // ---- S^T tiles from LDS: rows = keys, cols = q ----
    f32x16 sa[2];
#pragma unroll
    for (int st = 0; st < 2; st++) {
      f32x16 a;
#pragma unroll
      for (int i = 0; i < 16; i++) a[i] = 0.f;
#pragma unroll
      for (int c = 0; c < 4; c++) {
        short8 Kf = *(const short8*)&Kt[buf][st * 32 + lq][c * 16 + hh * 8];
        a = __builtin_amdgcn_mfma_f32_32x32x16_bf16(Kf, Qf[c], a, 0, 0, 0);
      }
      sa[st] = a;
    }
    // ---- bias + mask + collect (log2 domain) ----
    float sv[32];
    float mloc = -INFINITY;
#pragma unroll
    for (int st = 0; st < 2; st++)
#pragma unroll
      for (int rg = 0; rg < 4; rg++) {
        int krun = k0 + st * 32 + rg * 8 + hh * 4;
        float4u bv = *(const float4u*)(Tl + (krun - q + 31 + 1024));
        float4 nv = *(const float4*)(negT + b * S_ + krun);
#pragma unroll
        for (int i = 0; i < 4; i++) {
          float bvi = bv[i];
          float nvi = (i == 0) ? nv.x : (i == 1) ? nv.y : (i == 2) ? nv.z : nv.w;
          float t0 = (krun + i == q) ? bvi : (bvi + nvi);
          float s = fmaf(sa[st][rg * 4 + i], SCL_, t0);
          sv[st * 16 + rg * 4 + i] = s;
          mloc = fmaxf(mloc, s);
        }
      }
    float mx = fmaxf(mloc, __shfl_xor(mloc, 32));
    float mnew = fmaxf(m_run, mx);
    float alpha = exp2f(m_run - mnew);  // first iter: exp2(-inf)=0
    // ---- p = exp2(sv - mnew), pack bf16 to per-wave LDS, lane-local sum ----
    float lsum = 0.f;
#pragma unroll
    for (int st = 0; st < 2; st++)
#pragma unroll
      for (int rg = 0; rg < 4; rg++) {
        float p0 = exp2f(sv[st * 16 + rg * 4 + 0] - mnew);
        float p1 = exp2f(sv[st * 16 + rg * 4 + 1] - mnew);
        float p2 = exp2f(sv[st * 16 + rg * 4 + 2] - mnew);
        float p3 = exp2f(sv[st * 16 + rg * 4 + 3] - mnew);
        lsum += (p0 + p1) + (p2 + p3);
        *(uint2*)&Pt[w][lq][st * 32 + rg * 8 + hh * 4] = make_uint2(pk_bf16(p0, p1), pk_bf16(p2, p3));
      }
    lsum += __shfl_xor(lsum, 32);
    l_run = l_run * alpha + lsum;
    m_run = mnew;
#pragma unroll
    for (int dt = 0; dt < 2; dt++)
#pragma unroll
      for (int i = 0; i < 16; i++) Ot[dt][i] *= alpha;
    // ---- O^T += V^T . P  (Pt is wave-local; LDS ops in-order per wave) ----
    short8 Pf[4];
#pragma unroll
    for (int c = 0; c < 4; c++) Pf[c] = *(const short8*)&Pt[w][lq][c * 16 + hh * 8];
#pragma unroll
    for (int dt = 0; dt < 2; dt++) {
#pragma unroll
      for (int c = 0; c < 4; c++) {
        short8 Vf = *(const short8*)&Vt[buf][dt * 32 + lq][c * 16 + hh * 8];
        Ot[dt] = __builtin_amdgcn_mfma_f32_32x32x16_bf16(Vf, Pf[c], Ot[dt], 0, 0, 0);
      }
    }
    if (it < 15) {
      WRITELDS(buf ^ 1);
      __syncthreads();
    }
  }
  // ---- epilogue: lane holds col q; rows d = i+8*rg+4*hh (+32*dt) ----
  float inv = 1.f / l_run;
  float* aorow = ao + ((size_t)(b * S_ + q)) * H_ + head * 64;
#pragma unroll
  for (int dt = 0; dt < 2; dt++)
#pragma unroll
    for (int rg = 0; rg < 4; rg++) {
      float4 o = make_float4(Ot[dt][rg * 4 + 0] * inv, Ot[dt][rg * 4 + 1] * inv,
                             Ot[dt][rg * 4 + 2] * inv, Ot[dt][rg * 4 + 3] * inv);
      *(float4*)(aorow + dt * 32 + rg * 8 + hh * 4) = o;
    }
#undef LOADREGS
#undef WRITELDS
}

// ---------------------------------------------------------------------------
// k_resffn: x += ao@Wo + bo; ln2 over E=4; x += relu(ln2@Wf1+bf1)@Wf2 + bf2.
// One wave per token.
// ---------------------------------------------------------------------------
__global__ __launch_bounds__(256) void k_resffn(const float* __restrict__ ao,
                                                const float* __restrict__ Wo,
                                                const float* __restrict__ bo,
                                                const float* __restrict__ g2,
                                                const float* __restrict__ b2n,
                                                const float* __restrict__ Wf1,
                                                const float* __restrict__ bf1,
                                                const float* __restrict__ Wf2,
                                                const float* __restrict__ bf2,
                                                float* __restrict__ x) {
  int tok = blockIdx.x * 4 + (threadIdx.x >> 6);
  int lane = threadIdx.x & 63;
  const float* aor = ao + (size_t)tok * H_;
  float r0 = 0, r1 = 0, r2 = 0, r3 = 0;
#pragma unroll
  for (int k = 0; k < H_ / 64; k++) {
    int kk = lane + k * 64;
    float a = aor[kk];
    float4 w = *(const float4*)&Wo[kk * 4];
    r0 += a * w.x; r1 += a * w.y; r2 += a * w.z; r3 += a * w.w;
  }
#pragma unroll
  for (int o = 1; o < 64; o <<= 1) {
    r0 += __shfl_xor(r0, o); r1 += __shfl_xor(r1, o);
    r2 += __shfl_xor(r2, o); r3 += __shfl_xor(r3, o);
  }
  float4 xo = *(const float4*)&x[tok * 4];
  float x0 = xo.x + r0 + bo[0];
  float x1 = xo.y + r1 + bo[1];
  float x2 = xo.z + r2 + bo[2];
  float x3 = xo.w + r3 + bo[3];
  float mn = 0.25f * (x0 + x1 + x2 + x3);
  float d0 = x0 - mn, d1 = x1 - mn, d2 = x2 - mn, d3 = x3 - mn;
  float var = 0.25f * (d0 * d0 + d1 * d1 + d2 * d2 + d3 * d3);
  float rs = rsqrtf(var + EPS_);
  float l0 = d0 * rs * g2[0] + b2n[0];
  float l1 = d1 * rs * g2[1] + b2n[1];
  float l2 = d2 * rs * g2[2] + b2n[2];
  float l3 = d3 * rs * g2[3] + b2n[3];
  float f0 = 0, f1 = 0, f2 = 0, f3 = 0;
#pragma unroll
  for (int f4 = 0; f4 < FF_ / 64; f4++) {
    int f = lane + f4 * 64;
    float hh = bf1[f] + l0 * Wf1[f] + l1 * Wf1[FF_ + f] + l2 * Wf1[2 * FF_ + f] + l3 * Wf1[3 * FF_ + f];
    hh = fmaxf(hh, 0.f);
    float4 w2 = *(const float4*)&Wf2[f * 4];
    f0 += hh * w2.x; f1 += hh * w2.y; f2 += hh * w2.z; f3 += hh * w2.w;
  }
#pragma unroll
  for (int o = 1; o < 64; o <<= 1) {
    f0 += __shfl_xor(f0, o); f1 += __shfl_xor(f1, o);
    f2 += __shfl_xor(f2, o); f3 += __shfl_xor(f3, o);
  }
  x0 += f0 + bf2[0]; x1 += f1 + bf2[1]; x2 += f2 + bf2[2]; x3 += f3 + bf2[3];
  if (lane == 0) *(float4*)&x[tok * 4] = make_float4(x0, x1, x2, x3);
}

// ---------------------------------------------------------------------------
// k_out: out = x @ Wout + bout   (4096 x 4 x 17)
// ---------------------------------------------------------------------------
__global__ __launch_bounds__(256) void k_out(const float* __restrict__ x,
                                             const float* __restrict__ Wout,
                                             const float* __restrict__ bout,
                                             float* __restrict__ out) {
  int gid = blockIdx.x * 256 + threadIdx.x;
  if (gid >= BS_ * NT_) return;
  int tok = gid / NT_;
  int tt = gid - tok * NT_;
  float4 xr = ((const float4*)x)[tok];
  out[gid] = bout[tt] + xr.x * Wout[tt] + xr.y * Wout[NT_ + tt] + xr.z * Wout[2 * NT_ + tt] + xr.w * Wout[3 * NT_ + tt];
}

extern "C" void kernel_launch(void* const* d_in, const int* in_sizes, int n_in,
                              void* d_out, int out_size, void* d_ws, size_t ws_size,
                              hipStream_t stream) {
  const int* patches = (const int*)d_in[0];
  const int* mask = (const int*)d_in[1];
  const float* emb = (const float*)d_in[2];
  const float* Wi = (const float*)d_in[3];
  const float* bi = (const float*)d_in[4];
  const float* Wqkv = (const float*)d_in[5];
  const float* bqkv = (const float*)d_in[6];
  const float* Wo = (const float*)d_in[7];
  const float* bo = (const float*)d_in[8];
  const float* g1 = (const float*)d_in[9];
  const float* b1n = (const float*)d_in[10];
  const float* Wf1 = (const float*)d_in[11];
  const float* bf1 = (const float*)d_in[12];
  const float* Wf2 = (const float*)d_in[13];
  const float* bf2 = (const float*)d_in[14];
  const float* g2 = (const float*)d_in[15];
  const float* b2n = (const float*)d_in[16];
  const float* relemb = (const float*)d_in[17];
  const float* Wout = (const float*)d_in[18];
  const float* bout = (const float*)d_in[19];
  float* out = (float*)d_out;

  char* p = (char*)d_ws;
  float* x = (float*)p;          p += (size_t)BS_ * 4 * 4;
  float* T = (float*)p;          p += (size_t)L_ * 2112 * 4;
  float* negT = (float*)p;       p += (size_t)BS_ * 4;
  float* ao = (float*)p;         p += (size_t)BS_ * H_ * 4;
  ushort* xnbf = (ushort*)p;     p += (size_t)BS_ * H_ * 2;
  ushort* Wt = (ushort*)p;       p += (size_t)L_ * 1536 * 512 * 2;
  ushort* qbf = (ushort*)p;      p += (size_t)32 * 1024 * 64 * 2;
  ushort* kbf = (ushort*)p;      p += (size_t)32 * 1024 * 64 * 2;
  ushort* vTb = (ushort*)p;      p += (size_t)32 * 64 * 1024 * 2;

  k_init<<<dim3(49), dim3(256), 0, stream>>>(patches, mask, emb, relemb, x, T, negT);
  k_cvtw<<<dim3(1536), dim3(256), 0, stream>>>(Wqkv, Wt);
  for (int l = 0; l < L_; l++) {
    k_inln<<<dim3(BS_), dim3(256), 0, stream>>>(x, Wi + l * E_ * H_, bi + l * H_,
                                                g1 + l * H_, b1n + l * H_, xnbf);
    k_qkv<<<dim3(12, 32), dim3(256), 0, stream>>>(xnbf, Wt + (size_t)l * 1536 * 512,
                                                  bqkv + l * 3 * H_, qbf, kbf, vTb);
    k_attn<<<dim3(8, 8, 4), dim3(256), 0, stream>>>(qbf, kbf, vTb, T + l * 2112, negT, ao);
    k_resffn<<<dim3(1024), dim3(256), 0, stream>>>(ao, Wo + l * H_ * E_, bo + l * E_,
                                                   g2 + l * E_, b2n + l * E_,
                                                   Wf1 + l * E_ * FF_, bf1 + l * FF_,
                                                   Wf2 + l * FF_ * E_, bf2 + l * E_, x);
  }
  k_out<<<dim3(272), dim3(256), 0, stream>>>(x, Wout, bout, out);
}

// Round 5
// 384.305 us; speedup vs baseline: 5.2180x; 1.0978x over previous
//
#include <hip/hip_runtime.h>
#include <hip/hip_bf16.h>
#include <math.h>

#define B_ 4
#define S_ 1024
#define H_ 512
#define NH_ 8
#define HD_ 64
#define FF_ 1024
#define E_ 4
#define L_ 4
#define NT_ 17
#define BS_ 4096
#define EPS_ 1e-5f
#define L2E_ 1.4426950408889634f
#define SCL_ 0.18033688011112042f   // 0.125 * log2(e)
#define KSPLIT_ 4

typedef __attribute__((ext_vector_type(8))) short short8;
typedef __attribute__((ext_vector_type(16))) float f32x16;
typedef float float4u __attribute__((ext_vector_type(4), aligned(4)));

__device__ inline ushort bf16_rne(float f) {
  unsigned u = __builtin_bit_cast(unsigned, f);
  u += 0x7FFFu + ((u >> 16) & 1u);
  return (ushort)(u >> 16);
}
__device__ inline unsigned pk_bf16(float a, float b) {
  return (unsigned)bf16_rne(a) | ((unsigned)bf16_rne(b) << 16);
}
__device__ inline float ubf2f(ushort u) {
  return __builtin_bit_cast(float, ((unsigned)u) << 16);
}

// ---------------------------------------------------------------------------
// k_init: x = emb[patches] (mask -> emb[16]); negT[b*S+k] = mask? -1e30 : 0;
// T[l][j] (j in [0,2112)) = biasum[l][clip(1086-j,0,62)] * log2(e)
// ---------------------------------------------------------------------------
__global__ __launch_bounds__(256) void k_init(const int* __restrict__ patches,
                                              const int* __restrict__ mask,
                                              const float* __restrict__ emb,
                                              const float* __restrict__ relemb,
                                              float* __restrict__ x,
                                              float* __restrict__ T,
                                              float* __restrict__ negT) {
  int gid = blockIdx.x * 256 + threadIdx.x;
  if (gid < BS_) {
    int mk = mask[gid];
    int row = mk ? (NT_ - 1) : patches[gid];
    ((float4*)x)[gid] = ((const float4*)emb)[row];
    negT[gid] = mk ? -1e30f : 0.f;
  } else {
    int idx = gid - BS_;
    if (idx < L_ * 2112) {
      int l = idx / 2112, j = idx - l * 2112;
      int c = 1086 - j;
      c = c < 0 ? 0 : (c > 62 ? 62 : c);
      const float* src = relemb + (size_t)(l * 63 + c) * 64;
      float s = 0.f;
#pragma unroll
      for (int d = 0; d < 64; d++) s += src[d];
      T[idx] = s * L2E_;
    }
  }
}

// ---------------------------------------------------------------------------
// k_cvtw: Wqkv fp32 [l][k=512][n=1536] -> Wt bf16 [l][n][k]  (transposed)
// ---------------------------------------------------------------------------
__global__ __launch_bounds__(256) void k_cvtw(const float* __restrict__ W,
                                              ushort* __restrict__ Wt) {
  int id = blockIdx.x * 256 + threadIdx.x;  // total L*64*1536
  int n = id % 1536;
  int r = id / 1536;           // l*64 + kc
  int kc = r & 63, l = r >> 6;
  const float* src = W + (size_t)l * 512 * 1536 + n;
  ushort* dst = Wt + ((size_t)(l * 1536 + n)) * 512 + kc * 8;
  uint4 o;
  o.x = pk_bf16(src[(size_t)(kc * 8 + 0) * 1536], src[(size_t)(kc * 8 + 1) * 1536]);
  o.y = pk_bf16(src[(size_t)(kc * 8 + 2) * 1536], src[(size_t)(kc * 8 + 3) * 1536]);
  o.z = pk_bf16(src[(size_t)(kc * 8 + 4) * 1536], src[(size_t)(kc * 8 + 5) * 1536]);
  o.w = pk_bf16(src[(size_t)(kc * 8 + 6) * 1536], src[(size_t)(kc * 8 + 7) * 1536]);
  *(uint4*)dst = o;
}

// ---------------------------------------------------------------------------
// k_inln: xp = x @ Wi + bi ; xn = layernorm(xp)*g1 + b1n -> bf16. Block/token.
// ---------------------------------------------------------------------------
__global__ __launch_bounds__(256) void k_inln(const float* __restrict__ x,
                                              const float* __restrict__ Wi,
                                              const float* __restrict__ bi,
                                              const float* __restrict__ g1,
                                              const float* __restrict__ b1n,
                                              ushort* __restrict__ xnbf) {
  __shared__ float red_s[4], red_q[4];
  int tok = blockIdx.x;
  int t = threadIdx.x;
  float4 xr = ((const float4*)x)[tok];
  int j0 = 2 * t, j1 = 2 * t + 1;
  float xp0 = bi[j0] + xr.x * Wi[j0] + xr.y * Wi[H_ + j0] + xr.z * Wi[2 * H_ + j0] + xr.w * Wi[3 * H_ + j0];
  float xp1 = bi[j1] + xr.x * Wi[j1] + xr.y * Wi[H_ + j1] + xr.z * Wi[2 * H_ + j1] + xr.w * Wi[3 * H_ + j1];
  float s = xp0 + xp1;
  float q = xp0 * xp0 + xp1 * xp1;
#pragma unroll
  for (int o = 32; o > 0; o >>= 1) {
    s += __shfl_xor(s, o);
    q += __shfl_xor(q, o);
  }
  int wid = t >> 6;
  if ((t & 63) == 0) { red_s[wid] = s; red_q[wid] = q; }
  __syncthreads();
  s = red_s[0] + red_s[1] + red_s[2] + red_s[3];
  q = red_q[0] + red_q[1] + red_q[2] + red_q[3];
  float mean = s * (1.f / (float)H_);
  float var = q * (1.f / (float)H_) - mean * mean;
  float rs = rsqrtf(var + EPS_);
  float v0 = (xp0 - mean) * rs * g1[j0] + b1n[j0];
  float v1 = (xp1 - mean) * rs * g1[j1] + b1n[j1];
  ((unsigned*)xnbf)[tok * 256 + t] = pk_bf16(v0, v1);
}

// ---------------------------------------------------------------------------
// k_qkv: bf16 MFMA GEMM  C(4096x1536) = xn(4096x512) @ Wqkv + bias.
// 128x128 tile, BK=64, 4 waves each 64x64 (2x2 of 32x32 MFMA tiles).
// ---------------------------------------------------------------------------
__global__ __launch_bounds__(256) void k_qkv(const ushort* __restrict__ A,
                                             const ushort* __restrict__ Wt,
                                             const float* __restrict__ bias,
                                             ushort* __restrict__ qbf,
                                             ushort* __restrict__ kbf,
                                             ushort* __restrict__ vTb) {
  __shared__ ushort At[128][72];
  __shared__ ushort Bt[128][72];
  int t = threadIdx.x;
  int n0 = blockIdx.x * 128, m0 = blockIdx.y * 128;
  bool tr = (n0 < 1024);
  int w = t >> 6, lq = t & 31, hh = (t >> 5) & 1;
  int wm = (w & 1) * 64, wn = (w >> 1) * 64;
  f32x16 acc[2][2];
#pragma unroll
  for (int mt = 0; mt < 2; mt++)
#pragma unroll
    for (int nt = 0; nt < 2; nt++)
#pragma unroll
      for (int i = 0; i < 16; i++) acc[mt][nt][i] = 0.f;

  for (int k0 = 0; k0 < 512; k0 += 64) {
    __syncthreads();
#pragma unroll
    for (int j = 0; j < 4; j++) {
      int id = 256 * j + t;
      int row = id >> 3, u = id & 7;
      *(uint4*)&At[row][u * 8] = *(const uint4*)(A + (size_t)(m0 + row) * 512 + k0 + u * 8);
      *(uint4*)&Bt[row][u * 8] = *(const uint4*)(Wt + (size_t)(n0 + row) * 512 + k0 + u * 8);
    }
    __syncthreads();
#pragma unroll
    for (int kc = 0; kc < 4; kc++) {
      short8 af[2], bf[2];
#pragma unroll
      for (int mt = 0; mt < 2; mt++) af[mt] = *(const short8*)&At[wm + mt * 32 + lq][kc * 16 + hh * 8];
#pragma unroll
      for (int nt = 0; nt < 2; nt++) bf[nt] = *(const short8*)&Bt[wn + nt * 32 + lq][kc * 16 + hh * 8];
#pragma unroll
      for (int mt = 0; mt < 2; mt++)
#pragma unroll
        for (int nt = 0; nt < 2; nt++) {
          if (tr)
            acc[mt][nt] = __builtin_amdgcn_mfma_f32_32x32x16_bf16(bf[nt], af[mt], acc[mt][nt], 0, 0, 0);
          else
            acc[mt][nt] = __builtin_amdgcn_mfma_f32_32x32x16_bf16(af[mt], bf[nt], acc[mt][nt], 0, 0, 0);
        }
    }
  }

  if (tr) {
#pragma unroll
    for (int mt = 0; mt < 2; mt++) {
      int token = m0 + wm + mt * 32 + lq;
      int bb = token >> 10, sr = token & 1023;
#pragma unroll
      for (int nt = 0; nt < 2; nt++) {
        int nn = n0 + wn + nt * 32;
        int nloc = (nn < 512) ? nn : nn - 512;
        ushort* dst = (nn < 512) ? qbf : kbf;
        int hd = nloc >> 6;
        size_t rowbase = ((size_t)(bb * 8 + hd) * 1024 + sr) * 64;
#pragma unroll
        for (int rg = 0; rg < 4; rg++) {
          int nbase = nn + rg * 8 + hh * 4;
          float4 bv = *(const float4*)(bias + nbase);
          float v0 = acc[mt][nt][rg * 4 + 0] + bv.x;
          float v1 = acc[mt][nt][rg * 4 + 1] + bv.y;
          float v2 = acc[mt][nt][rg * 4 + 2] + bv.z;
          float v3 = acc[mt][nt][rg * 4 + 3] + bv.w;
          int d0 = (nloc & 63) + rg * 8 + hh * 4;
          *(uint2*)(dst + rowbase + d0) = make_uint2(pk_bf16(v0, v1), pk_bf16(v2, v3));
        }
      }
    }
  } else {
#pragma unroll
    for (int nt = 0; nt < 2; nt++) {
      int n = n0 + wn + nt * 32 + lq;
      int nloc = n - 1024;
      int hd = nloc >> 6, d = nloc & 63;
      float bb_ = bias[n];
#pragma unroll
      for (int mt = 0; mt < 2; mt++) {
#pragma unroll
        for (int rg = 0; rg < 4; rg++) {
          int tb = m0 + wm + mt * 32 + rg * 8 + hh * 4;
          int bb = tb >> 10, sr = tb & 1023;
          float v0 = acc[mt][nt][rg * 4 + 0] + bb_;
          float v1 = acc[mt][nt][rg * 4 + 1] + bb_;
          float v2 = acc[mt][nt][rg * 4 + 2] + bb_;
          float v3 = acc[mt][nt][rg * 4 + 3] + bb_;
          *(uint2*)(vTb + ((size_t)(bb * 8 + hd) * 64 + d) * 1024 + sr) =
              make_uint2(pk_bf16(v0, v1), pk_bf16(v2, v3));
        }
      }
    }
  }
}

// ---------------------------------------------------------------------------
// k_attn: bf16 MFMA flash attention, S^T form, FIXED-SCALE softmax (no max:
// scores = qk*scale + bias are structurally bounded |s| < ~60 log2-units,
// so exp2(s) can neither overflow nor destroy precision in fp32/bf16).
// K-split: block = (b, h, 128 q, 256-key chunk j). 4 waves, single-buffer
// LDS K/V shared by the 4 waves; global->reg prefetch of next tile overlaps
// compute.  Writes UNNORMALIZED O^T partials (bf16) + l partials; combine is
// fused into k_resffn.
// ---------------------------------------------------------------------------
__global__ __launch_bounds__(256, 4) void k_attn(const ushort* __restrict__ qbf,
                                                 const ushort* __restrict__ kbf,
                                                 const ushort* __restrict__ vTb,
                                                 const float* __restrict__ Tl,
                                                 const float* __restrict__ negT,
                                                 ushort* __restrict__ Opart,
                                                 float* __restrict__ lpart) {
  __shared__ ushort Kt[64][72];
  __shared__ ushort Vt[64][72];
  __shared__ ushort Pt[4][32][72];
  int t = threadIdx.x;
  int w = t >> 6, lane = t & 63;
  int lq = lane & 31, hh = lane >> 5;
  int qb = blockIdx.x & 7, j = blockIdx.x >> 3;
  int head = blockIdx.y, b = blockIdx.z;
  int bh = b * NH_ + head;
  int q = qb * 128 + w * 32 + lq;
  int kstart = j * 256;

  const ushort* qrow = qbf + ((size_t)(bh * S_ + q)) * 64;
  short8 Qf[4];
#pragma unroll
  for (int c = 0; c < 4; c++) Qf[c] = *(const short8*)(qrow + c * 16 + hh * 8);

  int srow0 = t >> 3, scol = (t & 7) * 8;
  const ushort* kbase = kbf + (size_t)bh * S_ * 64;
  const ushort* vbase = vTb + (size_t)bh * 64 * S_;

  uint4 kr0, kr1, vr0, vr1;
#define LOADREGS(k0_)                                                        \
  kr0 = *(const uint4*)(kbase + (size_t)((k0_) + srow0) * 64 + scol);        \
  kr1 = *(const uint4*)(kbase + (size_t)((k0_) + srow0 + 32) * 64 + scol);   \
  vr0 = *(const uint4*)(vbase + (size_t)srow0 * S_ + (k0_) + scol);          \
  vr1 = *(const uint4*)(vbase + (size_t)(srow0 + 32) * S_ + (k0_) + scol);
#define WRITELDS                                                             \
  *(uint4*)&Kt[srow0][scol] = kr0;                                           \
  *(uint4*)&Kt[srow0 + 32][scol] = kr1;                                      \
  *(uint4*)&Vt[srow0][scol] = vr0;                                           \
  *(uint4*)&Vt[srow0 + 32][scol] = vr1;

  float l_run = 0.f;
  f32x16 Ot[2];
#pragma unroll
  for (int dt = 0; dt < 2; dt++)
#pragma unroll
    for (int i = 0; i < 16; i++) Ot[dt][i] = 0.f;

  LOADREGS(kstart);

  for (int it = 0; it < 4; it++) {
    int k0 = kstart + it * 64;
    __syncthreads();  // prior iteration's LDS reads complete
    WRITELDS;
    __syncthreads();
    if (it < 3) { LOADREGS(k0 + 64); }
    // ---- S^T tiles from LDS: rows = keys, cols = q ----
    f32x16 sa[2];
#pragma unroll
    for (int st = 0; st < 2; st++) {
      f32x16 a;
#pragma unroll
      for (int i = 0; i < 16; i++) a[i] = 0.f;
#pragma unroll
      for (int c = 0; c < 4; c++) {
        short8 Kf = *(const short8*)&Kt[st * 32 + lq][c * 16 + hh * 8];
        a = __builtin_amdgcn_mfma_f32_32x32x16_bf16(Kf, Qf[c], a, 0, 0, 0);
      }
      sa[st] = a;
    }
    // ---- p = exp2(qk*scl + bias (+neg)), pack bf16, lane-local sum ----
#pragma unroll
    for (int st = 0; st < 2; st++)
#pragma unroll
      for (int rg = 0; rg < 4; rg++) {
        int krun = k0 + st * 32 + rg * 8 + hh * 4;
        float4u bv = *(const float4u*)(Tl + (krun - q + 31 + 1024));
        float4 nv = *(const float4*)(negT + b * S_ + krun);
        float p[4];
#pragma unroll
        for (int i = 0; i < 4; i++) {
          float nvi = (i == 0) ? nv.x : (i == 1) ? nv.y : (i == 2) ? nv.z : nv.w;
          float t0 = (krun + i == q) ? bv[i] : (bv[i] + nvi);
          p[i] = exp2f(fmaf(sa[st][rg * 4 + i], SCL_, t0));
          l_run += p[i];
        }
        *(uint2*)&Pt[w][lq][st * 32 + rg * 8 + hh * 4] =
            make_uint2(pk_bf16(p[0], p[1]), pk_bf16(p[2], p[3]));
      }
    // ---- O^T += V^T . P  (Pt wave-local; same-wave LDS order suffices) ----
    short8 Pf[4];
#pragma unroll
    for (int c = 0; c < 4; c++) Pf[c] = *(const short8*)&Pt[w][lq][c * 16 + hh * 8];
#pragma unroll
    for (int dt = 0; dt < 2; dt++) {
#pragma unroll
      for (int c = 0; c < 4; c++) {
        short8 Vf = *(const short8*)&Vt[dt * 32 + lq][c * 16 + hh * 8];
        Ot[dt] = __builtin_amdgcn_mfma_f32_32x32x16_bf16(Vf, Pf[c], Ot[dt], 0, 0, 0);
      }
    }
  }
  // ---- epilogue: unnormalized bf16 partials; lane holds col q ----
  ushort* orow = Opart + (size_t)j * (BS_ * H_) + ((size_t)(b * S_ + q)) * H_ + head * 64;
#pragma unroll
  for (int dt = 0; dt < 2; dt++)
#pragma unroll
    for (int rg = 0; rg < 4; rg++) {
      *(uint2*)(orow + dt * 32 + rg * 8 + hh * 4) =
          make_uint2(pk_bf16(Ot[dt][rg * 4 + 0], Ot[dt][rg * 4 + 1]),
                     pk_bf16(Ot[dt][rg * 4 + 2], Ot[dt][rg * 4 + 3]));
    }
  float l_tot = l_run + __shfl_xor(l_run, 32);
  if (hh == 0) lpart[((size_t)j * 32 + bh) * S_ + q] = l_tot;
#undef LOADREGS
#undef WRITELDS
}

// ---------------------------------------------------------------------------
// k_resffn: combine attention partials (Σ_j O_j)/(Σ_j l_j), then
// x += ao@Wo + bo; ln2 over E=4; x += relu(ln2@Wf1+bf1)@Wf2 + bf2.
// One wave per token.  Head of element kk = kk>>6 = k (since lane<64).
// ---------------------------------------------------------------------------
__global__ __launch_bounds__(256) void k_resffn(const ushort* __restrict__ Opart,
                                                const float* __restrict__ lpart,
                                                const float* __restrict__ Wo,
                                                const float* __restrict__ bo,
                                                const float* __restrict__ g2,
                                                const float* __restrict__ b2n,
                                                const float* __restrict__ Wf1,
                                                const float* __restrict__ bf1,
                                                const float* __restrict__ Wf2,
                                                const float* __restrict__ bf2,
                                                float* __restrict__ x) {
  int tok = blockIdx.x * 4 + (threadIdx.x >> 6);
  int lane = threadIdx.x & 63;
  int b = tok >> 10, qq = tok & 1023;
  const ushort* aor = Opart + (size_t)tok * H_;
  float r0 = 0, r1 = 0, r2 = 0, r3 = 0;
#pragma unroll
  for (int k = 0; k < H_ / 64; k++) {
    int kk = lane + k * 64;
    int lidx = (b * 8 + k) * 1024 + qq;
    float ls = lpart[lidx] + lpart[lidx + 32768] + lpart[lidx + 65536] + lpart[lidx + 98304];
    float a = ubf2f(aor[kk]) + ubf2f(aor[kk + 2097152]) +
              ubf2f(aor[kk + 2 * 2097152]) + ubf2f(aor[kk + 3 * 2097152]);
    a *= (1.f / ls);
    float4 w = *(const float4*)&Wo[kk * 4];
    r0 += a * w.x; r1 += a * w.y; r2 += a * w.z; r3 += a * w.w;
  }
#pragma unroll
  for (int o = 1; o < 64; o <<= 1) {
    r0 += __shfl_xor(r0, o); r1 += __shfl_xor(r1, o);
    r2 += __shfl_xor(r2, o); r3 += __shfl_xor(r3, o);
  }
  float4 xo = *(const float4*)&x[tok * 4];
  float x0 = xo.x + r0 + bo[0];
  float x1 = xo.y + r1 + bo[1];
  float x2 = xo.z + r2 + bo[2];
  float x3 = xo.w + r3 + bo[3];
  float mn = 0.25f * (x0 + x1 + x2 + x3);
  float d0 = x0 - mn, d1 = x1 - mn, d2 = x2 - mn, d3 = x3 - mn;
  float var = 0.25f * (d0 * d0 + d1 * d1 + d2 * d2 + d3 * d3);
  float rs = rsqrtf(var + EPS_);
  float l0 = d0 * rs * g2[0] + b2n[0];
  float l1 = d1 * rs * g2[1] + b2n[1];
  float l2 = d2 * rs * g2[2] + b2n[2];
  float l3 = d3 * rs * g2[3] + b2n[3];
  float f0 = 0, f1 = 0, f2 = 0, f3 = 0;
#pragma unroll
  for (int f4 = 0; f4 < FF_ / 64; f4++) {
    int f = lane + f4 * 64;
    float hh = bf1[f] + l0 * Wf1[f] + l1 * Wf1[FF_ + f] + l2 * Wf1[2 * FF_ + f] + l3 * Wf1[3 * FF_ + f];
    hh = fmaxf(hh, 0.f);
    float4 w2 = *(const float4*)&Wf2[f * 4];
    f0 += hh * w2.x; f1 += hh * w2.y; f2 += hh * w2.z; f3 += hh * w2.w;
  }
#pragma unroll
  for (int o = 1; o < 64; o <<= 1) {
    f0 += __shfl_xor(f0, o); f1 += __shfl_xor(f1, o);
    f2 += __shfl_xor(f2, o); f3 += __shfl_xor(f3, o);
  }
  x0 += f0 + bf2[0]; x1 += f1 + bf2[1]; x2 += f2 + bf2[2]; x3 += f3 + bf2[3];
  if (lane == 0) *(float4*)&x[tok * 4] = make_float4(x0, x1, x2, x3);
}

// ---------------------------------------------------------------------------
// k_out: out = x @ Wout + bout   (4096 x 4 x 17)
// ---------------------------------------------------------------------------
__global__ __launch_bounds__(256) void k_out(const float* __restrict__ x,
                                             const float* __restrict__ Wout,
                                             const float* __restrict__ bout,
                                             float* __restrict__ out) {
  int gid = blockIdx.x * 256 + threadIdx.x;
  if (gid >= BS_ * NT_) return;
  int tok = gid / NT_;
  int tt = gid - tok * NT_;
  float4 xr = ((const float4*)x)[tok];
  out[gid] = bout[tt] + xr.x * Wout[tt] + xr.y * Wout[NT_ + tt] + xr.z * Wout[2 * NT_ + tt] + xr.w * Wout[3 * NT_ + tt];
}

extern "C" void kernel_launch(void* const* d_in, const int* in_sizes, int n_in,
                              void* d_out, int out_size, void* d_ws, size_t ws_size,
                              hipStream_t stream) {
  const int* patches = (const int*)d_in[0];
  const int* mask = (const int*)d_in[1];
  const float* emb = (const float*)d_in[2];
  const float* Wi = (const float*)d_in[3];
  const float* bi = (const float*)d_in[4];
  const float* Wqkv = (const float*)d_in[5];
  const float* bqkv = (const float*)d_in[6];
  const float* Wo = (const float*)d_in[7];
  const float* bo = (const float*)d_in[8];
  const float* g1 = (const float*)d_in[9];
  const float* b1n = (const float*)d_in[10];
  const float* Wf1 = (const float*)d_in[11];
  const float* bf1 = (const float*)d_in[12];
  const float* Wf2 = (const float*)d_in[13];
  const float* bf2 = (const float*)d_in[14];
  const float* g2 = (const float*)d_in[15];
  const float* b2n = (const float*)d_in[16];
  const float* relemb = (const float*)d_in[17];
  const float* Wout = (const float*)d_in[18];
  const float* bout = (const float*)d_in[19];
  float* out = (float*)d_out;

  char* p = (char*)d_ws;
  float* x = (float*)p;          p += (size_t)BS_ * 4 * 4;
  float* T = (float*)p;          p += (size_t)L_ * 2112 * 4;
  float* negT = (float*)p;       p += (size_t)BS_ * 4;
  float* lpart = (float*)p;      p += (size_t)KSPLIT_ * 32 * 1024 * 4;
  ushort* Opart = (ushort*)p;    p += (size_t)KSPLIT_ * BS_ * H_ * 2;   // 16.8 MB
  ushort* xnbf = (ushort*)p;     p += (size_t)BS_ * H_ * 2;
  ushort* Wt = (ushort*)p;       p += (size_t)L_ * 1536 * 512 * 2;
  ushort* qbf = (ushort*)p;      p += (size_t)32 * 1024 * 64 * 2;
  ushort* kbf = (ushort*)p;      p += (size_t)32 * 1024 * 64 * 2;
  ushort* vTb = (ushort*)p;      p += (size_t)32 * 64 * 1024 * 2;

  k_init<<<dim3(49), dim3(256), 0, stream>>>(patches, mask, emb, relemb, x, T, negT);
  k_cvtw<<<dim3(1536), dim3(256), 0, stream>>>(Wqkv, Wt);
  for (int l = 0; l < L_; l++) {
    k_inln<<<dim3(BS_), dim3(256), 0, stream>>>(x, Wi + l * E_ * H_, bi + l * H_,
                                                g1 + l * H_, b1n + l * H_, xnbf);
    k_qkv<<<dim3(12, 32), dim3(256), 0, stream>>>(xnbf, Wt + (size_t)l * 1536 * 512,
                                                  bqkv + l * 3 * H_, qbf, kbf, vTb);
    k_attn<<<dim3(8 * KSPLIT_, 8, 4), dim3(256), 0, stream>>>(qbf, kbf, vTb, T + l * 2112,
                                                              negT, Opart, lpart);
    k_resffn<<<dim3(1024), dim3(256), 0, stream>>>(Opart, lpart, Wo + l * H_ * E_, bo + l * E_,
                                                   g2 + l * E_, b2n + l * E_,
                                                   Wf1 + l * E_ * FF_, bf1 + l * FF_,
                                                   Wf2 + l * FF_ * E_, bf2 + l * E_, x);
  }
  k_out<<<dim3(272), dim3(256), 0, stream>>>(x, Wout, bout, out);
}